// Round 8
// baseline (238.606 us; speedup 1.0000x reference)
//
#include <hip/hip_runtime.h>
#include <cstdint>
#include <cstddef>

// ---------------------------------------------------------------------------
// MHA: out = softmax(causal(mask((XWq)(XWk)^T/8))) (XWv) Wo + biases
// B=2, T=2048, D=1024, H=16, dk=64. bf16 MFMA, fp32 accumulate.
// R8: cvt pass shrunk to WEIGHTS ONLY (24 MB); gemm_qkv consumes fp32 X
//     directly (async fp32 A staging, 16-chunk XOR swizzle, frag = 2x b128
//     + packed cvt). v_cvt_pk_bf16_f32 (guarded, with compiling fallback)
//     for A-frag cvt and attn P-pack. Attention otherwise = R7 (register-
//     resident P, sigma-permuted V, balanced qc map, XCD-local bh).
// ---------------------------------------------------------------------------

typedef __bf16 bf16x8 __attribute__((ext_vector_type(8)));
typedef float f32x4 __attribute__((ext_vector_type(4)));

#define MFMA(a, b, c) __builtin_amdgcn_mfma_f32_16x16x32_bf16((a), (b), (c), 0, 0, 0)

static constexpr int D_MODEL = 1024;
static constexpr int T_ = 2048;
static constexpr int M_TOK = 4096;   // B*T

__device__ __forceinline__ unsigned short f32_to_bf16(float f) {   // RNE
    union { float f; uint32_t u; } v; v.f = f;
    uint32_t u = v.u;
    uint32_t r = u + 0x7fffu + ((u >> 16) & 1u);
    return (unsigned short)(r >> 16);
}

// pack two f32 -> two bf16 in one dword (RNE via HW instr when available)
__device__ __forceinline__ unsigned pack2(float a, float b) {
#if __has_builtin(__builtin_amdgcn_cvt_pk_bf16_f32)
    typedef __bf16 bf16x2v __attribute__((ext_vector_type(2)));
    union { bf16x2v v; unsigned u; } r;
    r.v = __builtin_amdgcn_cvt_pk_bf16_f32(a, b);
    return r.u;
#else
    union { float f; unsigned u; } x, y; x.f = a; y.f = b;
    return ((x.u + 0x8000u) >> 16) | ((y.u + 0x8000u) & 0xffff0000u);
#endif
}
__device__ __forceinline__ bf16x8 cvt8(f32x4 a, f32x4 b) {
    union { unsigned u[4]; bf16x8 v; } r;
    r.u[0] = pack2(a[0], a[1]); r.u[1] = pack2(a[2], a[3]);
    r.u[2] = pack2(b[0], b[1]); r.u[3] = pack2(b[2], b[3]);
    return r.v;
}

typedef __attribute__((address_space(1))) void* as1_ptr;
typedef __attribute__((address_space(3))) void* as3_ptr;
__device__ __forceinline__ void gload_lds16(const void* g, void* l) {
    // lane's 16B land at (wave-uniform l) + lane*16
    __builtin_amdgcn_global_load_lds((as1_ptr)(void*)g, (as3_ptr)l, 16, 0, 0);
}

// sigma: actual key (within 64) -> storage index matching PV MFMA k-slots.
__device__ __forceinline__ int keyperm(int k) {
    return (k & 32) | ((k & 12) << 1) | ((k & 16) >> 2) | (k & 3);
}

// --------------------------- weights fp32 -> bf16 ---------------------------
// dst (float4 units): Wq Wk Wv Wo, 256K float4 each.
__global__ __launch_bounds__(256) void cvt_w(
    const float* __restrict__ wq, const float* __restrict__ wk,
    const float* __restrict__ wv, const float* __restrict__ wo,
    ushort4* __restrict__ dst) {
    int i = blockIdx.x * blockDim.x + threadIdx.x;
    int w = i >> 18, idx = i & ((1 << 18) - 1);
    const float* s = (w == 0) ? wq : (w == 1) ? wk : (w == 2) ? wv : wo;
    float4 f = ((const float4*)s)[idx];
    ushort4 o;
    o.x = f32_to_bf16(f.x); o.y = f32_to_bf16(f.y);
    o.z = f32_to_bf16(f.z); o.w = f32_to_bf16(f.w);
    dst[i] = o;
}

// --------------------------- GEMM: C = A @ W^T + bias -----------------------
// Tile 128 x (NT16*32), BK=64, 4 waves 2x2, global_load_lds(16B), XOR swizzle.
// AFP32: A read directly as fp32 (32KB LDS tile, 16-chunk swizzle, frag =
// 2x b128 + cvt8). Else A bf16 (16KB, 8-chunk swizzle).
// MODE 0: bf16 row-major [M][1024] (Q,K; SWAPPED epilogue -> ushort4 stores).
// MODE 2: bf16 [B][H][64][Tperm] (V; UNswapped, t sigma-permuted per 64-blk).
// MODE 3: f32 row-major [M][1024] (SWAPPED -> float4 stores).
template<int MODE, int NT16, bool AFP32>
__device__ __forceinline__ void gemm_body(
    const void* __restrict__ Ap, const unsigned short* __restrict__ W,
    const float* __restrict__ bias, void* __restrict__ outp,
    unsigned short* As, unsigned short* Ws, int bx, int by)
{
    constexpr bool SWAP = (MODE != 2);
    const int tid = threadIdx.x;
    const int lane = tid & 63, wave = tid >> 6;
    const int wm = wave >> 1, wn = wave & 1;
    const int r16 = lane & 15, kg = lane >> 4;
    const int m_blk = by * 128, n_blk = bx * (NT16 * 32);

    const float* Af = (const float*)Ap;
    const unsigned short* Ab = (const unsigned short*)Ap;
    float* Asf = (float*)As;

    f32x4 acc[4][NT16];
    #pragma unroll
    for (int mt = 0; mt < 4; ++mt)
        #pragma unroll
        for (int nt = 0; nt < NT16; ++nt) acc[mt][nt] = (f32x4){0, 0, 0, 0};

    for (int k0 = 0; k0 < D_MODEL; k0 += 64) {
        __syncthreads();
        if (AFP32) {
            #pragma unroll
            for (int j = 0; j < 8; ++j) {       // A tile: 128x64 fp32 = 32 KB
                int si = j * 256 + tid;
                int row = si >> 4, ch = (si & 15) ^ (row & 15);
                gload_lds16(Af + (size_t)(m_blk + row) * D_MODEL + k0 + ch * 4,
                            (char*)As + (j * 256 + wave * 64) * 16);
            }
        } else {
            #pragma unroll
            for (int j = 0; j < 4; ++j) {       // A tile: 128x64 bf16 = 16 KB
                int si = j * 256 + tid;
                int row = si >> 3, cg = (si & 7) ^ (row & 7);
                gload_lds16(Ab + (size_t)(m_blk + row) * D_MODEL + k0 + cg * 8,
                            (char*)As + (j * 256 + wave * 64) * 16);
            }
        }
        #pragma unroll
        for (int j = 0; j < NT16; ++j) {        // W tile: (NT16*32)x64 bf16
            int si = j * 256 + tid;
            int row = si >> 3, cg = (si & 7) ^ (row & 7);
            gload_lds16(W + (size_t)(n_blk + row) * D_MODEL + k0 + cg * 8,
                        (char*)Ws + (j * 256 + wave * 64) * 16);
        }
        __syncthreads();                        // drains vmcnt
        #pragma unroll
        for (int kc = 0; kc < 2; ++kc) {
            bf16x8 af[4], wf[NT16];
            #pragma unroll
            for (int mt = 0; mt < 4; ++mt) {
                int row = wm * 64 + mt * 16 + r16;
                if (AFP32) {
                    int g = (kc * 4 + kg) * 2;
                    f32x4 c0 = *(const f32x4*)(Asf + row * 64 + ((g ^ (row & 15)) * 4));
                    f32x4 c1 = *(const f32x4*)(Asf + row * 64 + (((g + 1) ^ (row & 15)) * 4));
                    af[mt] = cvt8(c0, c1);
                } else {
                    af[mt] = *(const bf16x8*)(As + row * 64 + (((kc * 4 + kg) ^ (row & 7)) * 8));
                }
            }
            #pragma unroll
            for (int nt = 0; nt < NT16; ++nt) {
                int row = wn * (NT16 * 16) + nt * 16 + r16;
                wf[nt] = *(const bf16x8*)(Ws + row * 64 + (((kc * 4 + kg) ^ (row & 7)) * 8));
            }
            #pragma unroll
            for (int mt = 0; mt < 4; ++mt)
                #pragma unroll
                for (int nt = 0; nt < NT16; ++nt)
                    acc[mt][nt] = SWAP ? MFMA(wf[nt], af[mt], acc[mt][nt])
                                       : MFMA(af[mt], wf[nt], acc[mt][nt]);
        }
    }
    if (MODE == 2) {
        // UNswapped C/D: lane holds m = kg*4+r (t, consecutive), n = r16 fixed.
        #pragma unroll
        for (int nt = 0; nt < NT16; ++nt) {
            int n = n_blk + wn * (NT16 * 16) + nt * 16 + r16;
            float bn = bias[n];
            int hh = n >> 6, dki = n & 63;
            #pragma unroll
            for (int mt = 0; mt < 4; ++mt) {
                int m0 = m_blk + wm * 64 + mt * 16 + kg * 4;
                int mp = (m0 & ~63) | keyperm(m0 & 63);   // sigma within 64-blk
                int bb = mp >> 11, ti = mp & 2047;
                ushort4 pk;
                pk.x = f32_to_bf16(acc[mt][nt][0] + bn);
                pk.y = f32_to_bf16(acc[mt][nt][1] + bn);
                pk.z = f32_to_bf16(acc[mt][nt][2] + bn);
                pk.w = f32_to_bf16(acc[mt][nt][3] + bn);
                *(ushort4*)((unsigned short*)outp +
                    ((size_t)(bb * 16 + hh) * 64 + dki) * 2048 + ti) = pk;
            }
        }
    } else {
        // SWAPPED C/D: lane holds n = kg*4+r (consecutive), m = r16 fixed.
        #pragma unroll
        for (int nt = 0; nt < NT16; ++nt) {
            int n0 = n_blk + wn * (NT16 * 16) + nt * 16 + kg * 4;
            float4 bn4 = *(const float4*)(bias + n0);
            #pragma unroll
            for (int mt = 0; mt < 4; ++mt) {
                int m = m_blk + wm * 64 + mt * 16 + r16;
                if (MODE == 3) {
                    float4 st;
                    st.x = acc[mt][nt][0] + bn4.x; st.y = acc[mt][nt][1] + bn4.y;
                    st.z = acc[mt][nt][2] + bn4.z; st.w = acc[mt][nt][3] + bn4.w;
                    *(float4*)((float*)outp + (size_t)m * D_MODEL + n0) = st;
                } else {
                    ushort4 pk;
                    pk.x = f32_to_bf16(acc[mt][nt][0] + bn4.x);
                    pk.y = f32_to_bf16(acc[mt][nt][1] + bn4.y);
                    pk.z = f32_to_bf16(acc[mt][nt][2] + bn4.z);
                    pk.w = f32_to_bf16(acc[mt][nt][3] + bn4.w);
                    *(ushort4*)((unsigned short*)outp + (size_t)m * D_MODEL + n0) = pk;
                }
            }
        }
    }
}

__global__ __launch_bounds__(256) void gemm_qkv(
    const float* __restrict__ q, const float* __restrict__ k,
    const float* __restrict__ v, const unsigned short* __restrict__ Wqb,
    const unsigned short* __restrict__ Wkb, const unsigned short* __restrict__ Wvb,
    const float* __restrict__ bq, const float* __restrict__ bk, const float* __restrict__ bv,
    unsigned short* __restrict__ Qhp, unsigned short* __restrict__ Khp,
    unsigned short* __restrict__ Vtp)
{
    __shared__ __align__(16) unsigned short As[128 * 64 * 2];  // fp32 A tile
    __shared__ __align__(16) unsigned short Ws[128 * 64];
    const int z = blockIdx.z;
    const float* A = (z == 0) ? q : (z == 1) ? k : v;
    const unsigned short* W = (z == 0) ? Wqb : (z == 1) ? Wkb : Wvb;
    const float* bias = (z == 0) ? bq : (z == 1) ? bk : bv;
    if (z < 2)
        gemm_body<0, 4, true>(A, W, bias, (z == 0) ? (void*)Qhp : (void*)Khp,
                              As, Ws, blockIdx.x, blockIdx.y);
    else
        gemm_body<2, 4, true>(A, W, bias, (void*)Vtp, As, Ws,
                              blockIdx.x, blockIdx.y);
}

__global__ __launch_bounds__(256) void gemm_out(
    const unsigned short* __restrict__ ab, const unsigned short* __restrict__ Wob,
    const float* __restrict__ bo, float* __restrict__ outp)
{
    __shared__ __align__(16) unsigned short As[128 * 64];
    __shared__ __align__(16) unsigned short Ws[64 * 64];
    gemm_body<3, 2, false>(ab, Wob, bo, (void*)outp, As, Ws,
                           blockIdx.x, blockIdx.y);
}

// --------------------------- flash attention --------------------------------
// One 64-q chunk per block (4 waves x 16 q); qc quadruple map balances causal
// work per CU; bh fastest-varying for XCD KV L2 locality. Register-resident P
// (S^T = mfma(K,Q)); V stored key-permuted so PV B-frags are single b128
// reads. All-ones-mask fast path; causal only on the diagonal tile.
__global__ __launch_bounds__(256) void attn_fwd(
    const unsigned short* __restrict__ Qh, const unsigned short* __restrict__ Kh,
    const unsigned short* __restrict__ Vt, const int* __restrict__ mask,
    const int* __restrict__ causal_p, unsigned short* __restrict__ attnout)
{
    __shared__ __align__(16) unsigned short Ks[2][64 * 64];   // [key][dk] swz
    __shared__ __align__(16) unsigned short Vs[2][64 * 64];   // [dk][kperm] swz

    const int tid = threadIdx.x;
    const int lane = tid & 63, wave = tid >> 6;
    const int bh = blockIdx.x;
    const int y = blockIdx.y, y0 = y & 7, j4 = y >> 3;
    const int qc = (j4 == 0) ? y0 : (j4 == 1) ? (15 - y0)
                 : (j4 == 2) ? (16 + y0) : (31 - y0);
    const int b = bh >> 4, h = bh & 15;
    const int causal = *causal_p;
    const int r16 = lane & 15, kg = lane >> 4;

    const int q0 = qc * 64 + wave * 16;

    const unsigned short* Qb = Qh + (size_t)b * T_ * D_MODEL + h * 64;
    const unsigned short* Kb = Kh + (size_t)b * T_ * D_MODEL + h * 64;
    const unsigned short* Vb = Vt + (size_t)bh * 64 * T_;
    const int* mb = mask + b * T_;

    // Q fragments (B-operand for S^T: lane holds Q[q0+r16][kg*8+j])
    bf16x8 qf0 = *(const bf16x8*)(Qb + (size_t)(q0 + r16) * D_MODEL + kg * 8);
    bf16x8 qf1 = *(const bf16x8*)(Qb + (size_t)(q0 + r16) * D_MODEL + 32 + kg * 8);

    float l = 0.f;                       // per-lane partial for q = r16
    f32x4 o[4];
    #pragma unroll
    for (int f = 0; f < 4; ++f) o[f] = (f32x4){0, 0, 0, 0};
    const float sc2 = 0.18033688011112042f;   // log2(e) / sqrt(64)
    const int lim = wave * 16 + r16;          // causal limit on diagonal tile

    const int nT = causal ? (qc + 1) : 32;

    auto stage = [&](int buf, int t) {
        int t0 = t * 64;
        #pragma unroll
        for (int j = 0; j < 2; ++j) {
            int si = j * 256 + tid;
            int row = si >> 3, cg = (si & 7) ^ (row & 7);
            gload_lds16(Kb + (size_t)(t0 + row) * D_MODEL + cg * 8,
                        (char*)Ks[buf] + (j * 256 + wave * 64) * 16);
            gload_lds16(Vb + (size_t)row * T_ + t0 + cg * 8,
                        (char*)Vs[buf] + (j * 256 + wave * 64) * 16);
        }
    };

    stage(0, 0);
    for (int t = 0; t < nT; ++t) {
        __syncthreads();              // stage(t) complete
        if (t + 1 < nT) stage((t + 1) & 1, t + 1);   // prefetch over compute
        const unsigned short* Kst = Ks[t & 1];
        const unsigned short* Vst = Vs[t & 1];
        const int t0 = t * 64;
        const bool diag = causal && (t == qc);

        // key mask for this 64-key tile (wave-uniform)
        unsigned long long km = __ballot(mb[t0 + lane] != 0);

        // ---- S^T = K Q^T ----
        f32x4 s[4];
        #pragma unroll
        for (int c = 0; c < 4; ++c) {
            int key = c * 16 + r16;
            bf16x8 kf0 = *(const bf16x8*)(Kst + key * 64 + ((kg ^ (key & 7)) * 8));
            bf16x8 kf1 = *(const bf16x8*)(Kst + key * 64 + (((4 + kg) ^ (key & 7)) * 8));
            f32x4 z = (f32x4){0, 0, 0, 0};
            z = MFMA(kf0, qf0, z);
            z = MFMA(kf1, qf1, z);
            s[c] = z;
        }

        // ---- exp2 (+ masks only when needed; uniform branch) ----
        float pv[4][4];
        if (!diag && km == ~0ull) {
            #pragma unroll
            for (int c = 0; c < 4; ++c)
                #pragma unroll
                for (int r = 0; r < 4; ++r) {
                    float e = __builtin_amdgcn_exp2f(s[c][r] * sc2);
                    pv[c][r] = e; l += e;
                }
        } else {
            #pragma unroll
            for (int c = 0; c < 4; ++c) {
                unsigned mc = (unsigned)(km >> (c * 16));
                #pragma unroll
                for (int r = 0; r < 4; ++r) {
                    int kbit = kg * 4 + r;
                    bool ok = ((mc >> kbit) & 1) && (!diag || (c * 16 + kbit <= lim));
                    float e = ok ? __builtin_amdgcn_exp2f(s[c][r] * sc2) : 0.f;
                    pv[c][r] = e; l += e;
                }
            }
        }

        // ---- pack into bf16x8 PV A-operands (sigma order) ----
        union pk_t { unsigned u[4]; bf16x8 v; };
        pk_t pa[2];
        #pragma unroll
        for (int c = 0; c < 4; ++c) {
            int half = (c & 1) * 2;
            pa[c >> 1].u[half]     = pack2(pv[c][0], pv[c][1]);
            pa[c >> 1].u[half + 1] = pack2(pv[c][2], pv[c][3]);
        }

        // ---- O += P V: single b128 V-frags (permuted key storage) ----
        #pragma unroll
        for (int f = 0; f < 4; ++f) {
            int row = f * 16 + r16;     // dk row in Vs
            int rx = row & 7;
            #pragma unroll
            for (int cp = 0; cp < 2; ++cp) {
                int g = cp * 4 + kg;    // storage granule = MFMA k-granule
                bf16x8 vf = *(const bf16x8*)(Vst + row * 64 + ((g ^ rx) * 8));
                o[f] = MFMA(pa[cp].v, vf, o[f]);
            }
        }
    }

    // ---- epilogue: reduce l across kg groups, normalize, store [B,T,D] ----
    l += __shfl_xor(l, 16, 64); l += __shfl_xor(l, 32, 64);
    float inv = (l > 0.f) ? 1.0f / l : 0.f;   // every lane: inv for q=r16
    #pragma unroll
    for (int r = 0; r < 4; ++r) {
        int ql = kg * 4 + r;                  // local q row to store
        float iv = __shfl(inv, ql, 64);
        size_t base = ((size_t)(b * T_ + q0 + ql)) * D_MODEL + h * 64;
        #pragma unroll
        for (int f = 0; f < 4; ++f)
            attnout[base + f * 16 + r16] = f32_to_bf16(o[f][r] * iv);
    }
}

// --------------------------- launch -----------------------------------------
extern "C" void kernel_launch(void* const* d_in, const int* in_sizes, int n_in,
                              void* d_out, int out_size, void* d_ws, size_t ws_size,
                              hipStream_t stream) {
    const float* q  = (const float*)d_in[0];
    const float* k  = (const float*)d_in[1];
    const float* v  = (const float*)d_in[2];
    const float* Wq = (const float*)d_in[3];
    const float* bq = (const float*)d_in[4];
    const float* Wk = (const float*)d_in[5];
    const float* bk = (const float*)d_in[6];
    const float* Wv = (const float*)d_in[7];
    const float* bv = (const float*)d_in[8];
    const float* Wo = (const float*)d_in[9];
    const float* bo = (const float*)d_in[10];
    const int* mask   = (const int*)d_in[11];
    const int* causal = (const int*)d_in[12];

    const size_t SZ_TOK = (size_t)M_TOK * D_MODEL;   // 4M elems
    const size_t SZ_W   = (size_t)D_MODEL * D_MODEL; // 1M elems

    unsigned short* Wqb = (unsigned short*)d_ws;
    unsigned short* Wkb = Wqb + SZ_W;
    unsigned short* Wvb = Wkb + SZ_W;
    unsigned short* Wob = Wvb + SZ_W;
    unsigned short* Qhp = Wob + SZ_W;
    unsigned short* Khp = Qhp + SZ_TOK;
    unsigned short* Vtp = Khp + SZ_TOK;
    unsigned short* ab  = Vtp + SZ_TOK;              // 40 MB total

    cvt_w<<<4096, 256, 0, stream>>>(Wq, Wk, Wv, Wo, (ushort4*)Wqb);

    gemm_qkv<<<dim3(D_MODEL / 128, M_TOK / 128, 3), 256, 0, stream>>>(
        q, k, v, Wqb, Wkb, Wvb, bq, bk, bv, Qhp, Khp, Vtp);

    attn_fwd<<<dim3(32, 32), 256, 0, stream>>>(Qhp, Khp, Vtp, mask, causal, ab);

    gemm_out<<<dim3(D_MODEL / 64, M_TOK / 128), 256, 0, stream>>>(ab, Wob, bo,
                                                                  (float*)d_out);
}

// Round 9
// 229.786 us; speedup vs baseline: 1.0384x; 1.0384x over previous
//
#include <hip/hip_runtime.h>
#include <cstdint>
#include <cstddef>

// ---------------------------------------------------------------------------
// MHA: out = softmax(causal(mask((XWq)(XWk)^T/8))) (XWv) Wo + biases
// B=2, T=2048, D=1024, H=16, dk=64. bf16 MFMA, fp32 accumulate.
// R9: revert R8's fp32-A staging (FETCH doubled, 80us). GEMMs now use the
//     attn-proven ROTATED double-buffer at BK=32: barrier -> issue stage(t+1)
//     -> compute(t); the vmcnt drain for stage(t+1) lands at the NEXT barrier
//     so staging overlaps a full compute step. LDS stays 32 KB (qkv) /
//     24 KB (out) so occupancy is unchanged. 4-granule XOR swizzle
//     p = g ^ (row&3) ^ ((row>>2)&3) keeps frag reads 2-way (free).
//     cvt_all restored; attn unchanged from R8.
// ---------------------------------------------------------------------------

typedef __bf16 bf16x8 __attribute__((ext_vector_type(8)));
typedef float f32x4 __attribute__((ext_vector_type(4)));

#define MFMA(a, b, c) __builtin_amdgcn_mfma_f32_16x16x32_bf16((a), (b), (c), 0, 0, 0)

static constexpr int D_MODEL = 1024;
static constexpr int T_ = 2048;
static constexpr int M_TOK = 4096;   // B*T

__device__ __forceinline__ unsigned short f32_to_bf16(float f) {   // RNE
    union { float f; uint32_t u; } v; v.f = f;
    uint32_t u = v.u;
    uint32_t r = u + 0x7fffu + ((u >> 16) & 1u);
    return (unsigned short)(r >> 16);
}

// pack two f32 -> two bf16 in one dword (HW instr when available)
__device__ __forceinline__ unsigned pack2(float a, float b) {
#if __has_builtin(__builtin_amdgcn_cvt_pk_bf16_f32)
    typedef __bf16 bf16x2v __attribute__((ext_vector_type(2)));
    union { bf16x2v v; unsigned u; } r;
    r.v = __builtin_amdgcn_cvt_pk_bf16_f32(a, b);
    return r.u;
#else
    union { float f; unsigned u; } x, y; x.f = a; y.f = b;
    return ((x.u + 0x8000u) >> 16) | ((y.u + 0x8000u) & 0xffff0000u);
#endif
}

typedef __attribute__((address_space(1))) void* as1_ptr;
typedef __attribute__((address_space(3))) void* as3_ptr;
__device__ __forceinline__ void gload_lds16(const void* g, void* l) {
    // lane's 16B land at (wave-uniform l) + lane*16
    __builtin_amdgcn_global_load_lds((as1_ptr)(void*)g, (as3_ptr)l, 16, 0, 0);
}

// sigma: actual key (within 64) -> storage index matching PV MFMA k-slots.
__device__ __forceinline__ int keyperm(int k) {
    return (k & 32) | ((k & 12) << 1) | ((k & 16) >> 2) | (k & 3);
}

// --------------------------- fused fp32 -> bf16 convert ---------------------
// dst (float4 units): q[0,1M) k[1M,2M) v[2M,3M) Wq Wk Wv Wo [3M..4M)
__global__ __launch_bounds__(256) void cvt_all(
    const float* __restrict__ q, const float* __restrict__ k,
    const float* __restrict__ v, const float* __restrict__ wq,
    const float* __restrict__ wk, const float* __restrict__ wv,
    const float* __restrict__ wo, ushort4* __restrict__ dst) {
    int i = blockIdx.x * blockDim.x + threadIdx.x;
    constexpr int R = 1 << 20;        // 1M float4 per token tensor
    const float* s;
    int idx;
    if (i < 3 * R) {
        s = (i < R) ? q : (i < 2 * R) ? k : v;
        idx = i & (R - 1);
    } else {
        int j = i - 3 * R;
        int w = j >> 18;
        s = (w == 0) ? wq : (w == 1) ? wk : (w == 2) ? wv : wo;
        idx = j & ((1 << 18) - 1);
    }
    float4 f = ((const float4*)s)[idx];
    ushort4 o;
    o.x = f32_to_bf16(f.x); o.y = f32_to_bf16(f.y);
    o.z = f32_to_bf16(f.z); o.w = f32_to_bf16(f.w);
    dst[i] = o;
}

// --------------------------- GEMM: C = A @ W^T + bias -----------------------
// Tile 128 x (NT16*32), BK=32, 32 k-steps, rotated double-buffer (attn
// pattern): sync -> stage(t+1) -> compute(t). 4 waves 2x2; wave tile
// 64 x (NT16*16); per wave per step: (4+NT16) ds_read_b128 + 4*NT16 MFMA.
// Swizzle: logical granule g at physical p = g ^ (row&3) ^ ((row>>2)&3).
// MODE 0: bf16 row-major [M][1024] (Q,K; SWAPPED epilogue -> ushort4 stores).
// MODE 2: bf16 [B][H][64][Tperm] (V; UNswapped, t sigma-permuted per 64-blk).
// MODE 3: f32 row-major [M][1024] (SWAPPED -> float4 stores).
template<int MODE, int NT16>
__device__ __forceinline__ void gemm_body(
    const unsigned short* __restrict__ A, const unsigned short* __restrict__ W,
    const float* __restrict__ bias, void* __restrict__ outp,
    unsigned short* As, unsigned short* Ws, int bx, int by)
{
    constexpr bool SWAP = (MODE != 2);
    constexpr int NROW_W = NT16 * 32;
    const int tid = threadIdx.x;
    const int lane = tid & 63, wave = tid >> 6;
    const int wm = wave >> 1, wn = wave & 1;
    const int r16 = lane & 15, kg = lane >> 4;
    const int m_blk = by * 128, n_blk = bx * (NT16 * 32);

    f32x4 acc[4][NT16];
    #pragma unroll
    for (int mt = 0; mt < 4; ++mt)
        #pragma unroll
        for (int nt = 0; nt < NT16; ++nt) acc[mt][nt] = (f32x4){0, 0, 0, 0};

    auto stage = [&](int buf, int ks) {
        const int k0 = ks * 32;
        unsigned short* Ab = As + buf * (128 * 32);
        unsigned short* Wb = Ws + buf * (NROW_W * 32);
        #pragma unroll
        for (int j = 0; j < 2; ++j) {           // A tile: 128x32 bf16 = 8 KB
            int si = j * 256 + tid;
            int row = si >> 2;
            int ch = (si & 3) ^ (row & 3) ^ ((row >> 2) & 3);
            gload_lds16(A + (size_t)(m_blk + row) * D_MODEL + k0 + ch * 8,
                        (char*)Ab + (j * 256 + wave * 64) * 16);
        }
        #pragma unroll
        for (int j = 0; j < NROW_W / 64; ++j) { // W tile: NROW_W x 32 bf16
            int si = j * 256 + tid;
            int row = si >> 2;
            int ch = (si & 3) ^ (row & 3) ^ ((row >> 2) & 3);
            gload_lds16(W + (size_t)(n_blk + row) * D_MODEL + k0 + ch * 8,
                        (char*)Wb + (j * 256 + wave * 64) * 16);
        }
    };

    stage(0, 0);
    for (int ks = 0; ks < 32; ++ks) {
        __syncthreads();                        // drains stage(ks); frees other buf
        if (ks + 1 < 32) stage((ks + 1) & 1, ks + 1);   // overlaps compute below
        const unsigned short* Ab = As + (ks & 1) * (128 * 32);
        const unsigned short* Wb = Ws + (ks & 1) * (NROW_W * 32);
        bf16x8 af[4], wf[NT16];
        #pragma unroll
        for (int mt = 0; mt < 4; ++mt) {
            int row = wm * 64 + mt * 16 + r16;
            int fx = (row & 3) ^ ((row >> 2) & 3);
            af[mt] = *(const bf16x8*)(Ab + row * 32 + ((kg ^ fx) * 8));
        }
        #pragma unroll
        for (int nt = 0; nt < NT16; ++nt) {
            int row = wn * (NT16 * 16) + nt * 16 + r16;
            int fx = (row & 3) ^ ((row >> 2) & 3);
            wf[nt] = *(const bf16x8*)(Wb + row * 32 + ((kg ^ fx) * 8));
        }
        #pragma unroll
        for (int mt = 0; mt < 4; ++mt)
            #pragma unroll
            for (int nt = 0; nt < NT16; ++nt)
                acc[mt][nt] = SWAP ? MFMA(wf[nt], af[mt], acc[mt][nt])
                                   : MFMA(af[mt], wf[nt], acc[mt][nt]);
    }

    if (MODE == 2) {
        // UNswapped C/D: lane holds m = kg*4+r (t, consecutive), n = r16 fixed.
        #pragma unroll
        for (int nt = 0; nt < NT16; ++nt) {
            int n = n_blk + wn * (NT16 * 16) + nt * 16 + r16;
            float bn = bias[n];
            int hh = n >> 6, dki = n & 63;
            #pragma unroll
            for (int mt = 0; mt < 4; ++mt) {
                int m0 = m_blk + wm * 64 + mt * 16 + kg * 4;
                int mp = (m0 & ~63) | keyperm(m0 & 63);   // sigma within 64-blk
                int bb = mp >> 11, ti = mp & 2047;
                ushort4 pk;
                pk.x = f32_to_bf16(acc[mt][nt][0] + bn);
                pk.y = f32_to_bf16(acc[mt][nt][1] + bn);
                pk.z = f32_to_bf16(acc[mt][nt][2] + bn);
                pk.w = f32_to_bf16(acc[mt][nt][3] + bn);
                *(ushort4*)((unsigned short*)outp +
                    ((size_t)(bb * 16 + hh) * 64 + dki) * 2048 + ti) = pk;
            }
        }
    } else {
        // SWAPPED C/D: lane holds n = kg*4+r (consecutive), m = r16 fixed.
        #pragma unroll
        for (int nt = 0; nt < NT16; ++nt) {
            int n0 = n_blk + wn * (NT16 * 16) + nt * 16 + kg * 4;
            float4 bn4 = *(const float4*)(bias + n0);
            #pragma unroll
            for (int mt = 0; mt < 4; ++mt) {
                int m = m_blk + wm * 64 + mt * 16 + r16;
                if (MODE == 3) {
                    float4 st;
                    st.x = acc[mt][nt][0] + bn4.x; st.y = acc[mt][nt][1] + bn4.y;
                    st.z = acc[mt][nt][2] + bn4.z; st.w = acc[mt][nt][3] + bn4.w;
                    *(float4*)((float*)outp + (size_t)m * D_MODEL + n0) = st;
                } else {
                    ushort4 pk;
                    pk.x = f32_to_bf16(acc[mt][nt][0] + bn4.x);
                    pk.y = f32_to_bf16(acc[mt][nt][1] + bn4.y);
                    pk.z = f32_to_bf16(acc[mt][nt][2] + bn4.z);
                    pk.w = f32_to_bf16(acc[mt][nt][3] + bn4.w);
                    *(ushort4*)((unsigned short*)outp + (size_t)m * D_MODEL + n0) = pk;
                }
            }
        }
    }
}

__global__ __launch_bounds__(256) void gemm_qkv(
    const unsigned short* __restrict__ qb, const unsigned short* __restrict__ kb,
    const unsigned short* __restrict__ vb, const unsigned short* __restrict__ Wqb,
    const unsigned short* __restrict__ Wkb, const unsigned short* __restrict__ Wvb,
    const float* __restrict__ bq, const float* __restrict__ bk, const float* __restrict__ bv,
    unsigned short* __restrict__ Qhp, unsigned short* __restrict__ Khp,
    unsigned short* __restrict__ Vtp)
{
    __shared__ __align__(16) unsigned short As[2 * 128 * 32];  // 16 KB
    __shared__ __align__(16) unsigned short Ws[2 * 128 * 32];  // 16 KB
    const int z = blockIdx.z;
    const unsigned short* A = (z == 0) ? qb : (z == 1) ? kb : vb;
    const unsigned short* W = (z == 0) ? Wqb : (z == 1) ? Wkb : Wvb;
    const float* bias = (z == 0) ? bq : (z == 1) ? bk : bv;
    if (z < 2)
        gemm_body<0, 4>(A, W, bias, (z == 0) ? (void*)Qhp : (void*)Khp,
                        As, Ws, blockIdx.x, blockIdx.y);
    else
        gemm_body<2, 4>(A, W, bias, (void*)Vtp, As, Ws, blockIdx.x, blockIdx.y);
}

__global__ __launch_bounds__(256) void gemm_out(
    const unsigned short* __restrict__ ab, const unsigned short* __restrict__ Wob,
    const float* __restrict__ bo, float* __restrict__ outp)
{
    __shared__ __align__(16) unsigned short As[2 * 128 * 32];  // 16 KB
    __shared__ __align__(16) unsigned short Ws[2 * 64 * 32];   // 8 KB
    gemm_body<3, 2>(ab, Wob, bo, (void*)outp, As, Ws, blockIdx.x, blockIdx.y);
}

// --------------------------- flash attention --------------------------------
// One 64-q chunk per block (4 waves x 16 q); qc quadruple map balances causal
// work per CU; bh fastest-varying for XCD KV L2 locality. Register-resident P
// (S^T = mfma(K,Q)); V stored key-permuted so PV B-frags are single b128
// reads. All-ones-mask fast path; causal only on the diagonal tile.
__global__ __launch_bounds__(256) void attn_fwd(
    const unsigned short* __restrict__ Qh, const unsigned short* __restrict__ Kh,
    const unsigned short* __restrict__ Vt, const int* __restrict__ mask,
    const int* __restrict__ causal_p, unsigned short* __restrict__ attnout)
{
    __shared__ __align__(16) unsigned short Ks[2][64 * 64];   // [key][dk] swz
    __shared__ __align__(16) unsigned short Vs[2][64 * 64];   // [dk][kperm] swz

    const int tid = threadIdx.x;
    const int lane = tid & 63, wave = tid >> 6;
    const int bh = blockIdx.x;
    const int y = blockIdx.y, y0 = y & 7, j4 = y >> 3;
    const int qc = (j4 == 0) ? y0 : (j4 == 1) ? (15 - y0)
                 : (j4 == 2) ? (16 + y0) : (31 - y0);
    const int b = bh >> 4, h = bh & 15;
    const int causal = *causal_p;
    const int r16 = lane & 15, kg = lane >> 4;

    const int q0 = qc * 64 + wave * 16;

    const unsigned short* Qb = Qh + (size_t)b * T_ * D_MODEL + h * 64;
    const unsigned short* Kb = Kh + (size_t)b * T_ * D_MODEL + h * 64;
    const unsigned short* Vb = Vt + (size_t)bh * 64 * T_;
    const int* mb = mask + b * T_;

    // Q fragments (B-operand for S^T: lane holds Q[q0+r16][kg*8+j])
    bf16x8 qf0 = *(const bf16x8*)(Qb + (size_t)(q0 + r16) * D_MODEL + kg * 8);
    bf16x8 qf1 = *(const bf16x8*)(Qb + (size_t)(q0 + r16) * D_MODEL + 32 + kg * 8);

    float l = 0.f;                       // per-lane partial for q = r16
    f32x4 o[4];
    #pragma unroll
    for (int f = 0; f < 4; ++f) o[f] = (f32x4){0, 0, 0, 0};
    const float sc2 = 0.18033688011112042f;   // log2(e) / sqrt(64)
    const int lim = wave * 16 + r16;          // causal limit on diagonal tile

    const int nT = causal ? (qc + 1) : 32;

    auto stage = [&](int buf, int t) {
        int t0 = t * 64;
        #pragma unroll
        for (int j = 0; j < 2; ++j) {
            int si = j * 256 + tid;
            int row = si >> 3, cg = (si & 7) ^ (row & 7);
            gload_lds16(Kb + (size_t)(t0 + row) * D_MODEL + cg * 8,
                        (char*)Ks[buf] + (j * 256 + wave * 64) * 16);
            gload_lds16(Vb + (size_t)row * T_ + t0 + cg * 8,
                        (char*)Vs[buf] + (j * 256 + wave * 64) * 16);
        }
    };

    stage(0, 0);
    for (int t = 0; t < nT; ++t) {
        __syncthreads();              // stage(t) complete
        if (t + 1 < nT) stage((t + 1) & 1, t + 1);   // prefetch over compute
        const unsigned short* Kst = Ks[t & 1];
        const unsigned short* Vst = Vs[t & 1];
        const int t0 = t * 64;
        const bool diag = causal && (t == qc);

        // key mask for this 64-key tile (wave-uniform)
        unsigned long long km = __ballot(mb[t0 + lane] != 0);

        // ---- S^T = K Q^T ----
        f32x4 s[4];
        #pragma unroll
        for (int c = 0; c < 4; ++c) {
            int key = c * 16 + r16;
            bf16x8 kf0 = *(const bf16x8*)(Kst + key * 64 + ((kg ^ (key & 7)) * 8));
            bf16x8 kf1 = *(const bf16x8*)(Kst + key * 64 + (((4 + kg) ^ (key & 7)) * 8));
            f32x4 z = (f32x4){0, 0, 0, 0};
            z = MFMA(kf0, qf0, z);
            z = MFMA(kf1, qf1, z);
            s[c] = z;
        }

        // ---- exp2 (+ masks only when needed; uniform branch) ----
        float pv[4][4];
        if (!diag && km == ~0ull) {
            #pragma unroll
            for (int c = 0; c < 4; ++c)
                #pragma unroll
                for (int r = 0; r < 4; ++r) {
                    float e = __builtin_amdgcn_exp2f(s[c][r] * sc2);
                    pv[c][r] = e; l += e;
                }
        } else {
            #pragma unroll
            for (int c = 0; c < 4; ++c) {
                unsigned mc = (unsigned)(km >> (c * 16));
                #pragma unroll
                for (int r = 0; r < 4; ++r) {
                    int kbit = kg * 4 + r;
                    bool ok = ((mc >> kbit) & 1) && (!diag || (c * 16 + kbit <= lim));
                    float e = ok ? __builtin_amdgcn_exp2f(s[c][r] * sc2) : 0.f;
                    pv[c][r] = e; l += e;
                }
            }
        }

        // ---- pack into bf16x8 PV A-operands (sigma order) ----
        union pk_t { unsigned u[4]; bf16x8 v; };
        pk_t pa[2];
        #pragma unroll
        for (int c = 0; c < 4; ++c) {
            int half = (c & 1) * 2;
            pa[c >> 1].u[half]     = pack2(pv[c][0], pv[c][1]);
            pa[c >> 1].u[half + 1] = pack2(pv[c][2], pv[c][3]);
        }

        // ---- O += P V: single b128 V-frags (permuted key storage) ----
        #pragma unroll
        for (int f = 0; f < 4; ++f) {
            int row = f * 16 + r16;     // dk row in Vs
            int rx = row & 7;
            #pragma unroll
            for (int cp = 0; cp < 2; ++cp) {
                int g = cp * 4 + kg;    // storage granule = MFMA k-granule
                bf16x8 vf = *(const bf16x8*)(Vst + row * 64 + ((g ^ rx) * 8));
                o[f] = MFMA(pa[cp].v, vf, o[f]);
            }
        }
    }

    // ---- epilogue: reduce l across kg groups, normalize, store [B,T,D] ----
    l += __shfl_xor(l, 16, 64); l += __shfl_xor(l, 32, 64);
    float inv = (l > 0.f) ? 1.0f / l : 0.f;   // every lane: inv for q=r16
    #pragma unroll
    for (int r = 0; r < 4; ++r) {
        int ql = kg * 4 + r;                  // local q row to store
        float iv = __shfl(inv, ql, 64);
        size_t base = ((size_t)(b * T_ + q0 + ql)) * D_MODEL + h * 64;
        #pragma unroll
        for (int f = 0; f < 4; ++f)
            attnout[base + f * 16 + r16] = f32_to_bf16(o[f][r] * iv);
    }
}

// --------------------------- launch -----------------------------------------
extern "C" void kernel_launch(void* const* d_in, const int* in_sizes, int n_in,
                              void* d_out, int out_size, void* d_ws, size_t ws_size,
                              hipStream_t stream) {
    const float* q  = (const float*)d_in[0];
    const float* k  = (const float*)d_in[1];
    const float* v  = (const float*)d_in[2];
    const float* Wq = (const float*)d_in[3];
    const float* bq = (const float*)d_in[4];
    const float* Wk = (const float*)d_in[5];
    const float* bk = (const float*)d_in[6];
    const float* Wv = (const float*)d_in[7];
    const float* bv = (const float*)d_in[8];
    const float* Wo = (const float*)d_in[9];
    const float* bo = (const float*)d_in[10];
    const int* mask   = (const int*)d_in[11];
    const int* causal = (const int*)d_in[12];

    const size_t SZ_TOK = (size_t)M_TOK * D_MODEL;   // 4M elems
    const size_t SZ_W   = (size_t)D_MODEL * D_MODEL; // 1M elems

    unsigned short* qb  = (unsigned short*)d_ws;
    unsigned short* kb  = qb  + SZ_TOK;
    unsigned short* vb  = kb  + SZ_TOK;
    unsigned short* Wqb = vb  + SZ_TOK;
    unsigned short* Wkb = Wqb + SZ_W;
    unsigned short* Wvb = Wkb + SZ_W;
    unsigned short* Wob = Wvb + SZ_W;
    unsigned short* Qhp = Wob + SZ_W;
    unsigned short* Khp = Qhp + SZ_TOK;
    unsigned short* Vtp = Khp + SZ_TOK;
    unsigned short* ab  = Vtp + SZ_TOK;              // 64 MB total

    cvt_all<<<16384, 256, 0, stream>>>(q, k, v, Wq, Wk, Wv, Wo, (ushort4*)qb);

    gemm_qkv<<<dim3(D_MODEL / 128, M_TOK / 128, 3), 256, 0, stream>>>(
        qb, kb, vb, Wqb, Wkb, Wvb, bq, bk, bv, Qhp, Khp, Vtp);

    attn_fwd<<<dim3(32, 32), 256, 0, stream>>>(Qhp, Khp, Vtp, mask, causal, ab);

    gemm_out<<<dim3(D_MODEL / 64, M_TOK / 128), 256, 0, stream>>>(ab, Wob, bo,
                                                                  (float*)d_out);
}